// Round 5
// baseline (2496.434 us; speedup 1.0000x reference)
//
#include <hip/hip_runtime.h>

#define D_DIM 1024
#define B_ROWS 65536

typedef unsigned short u16;
typedef __attribute__((ext_vector_type(8))) __bf16 bf16x8;
typedef __attribute__((ext_vector_type(4))) float f32x4;
typedef __attribute__((ext_vector_type(8))) unsigned short u16x8;

typedef const __attribute__((address_space(1))) void* gas_cptr;
typedef __attribute__((address_space(3))) void* las_ptr;

__device__ __forceinline__ u16 f2bf(float f) {
  union { float fv; unsigned int i; } v; v.fv = f;
  return (u16)((v.i + 0x7FFFu + ((v.i >> 16) & 1u)) >> 16);
}
__device__ __forceinline__ float bf2f(u16 u) {
  union { unsigned int i; float f; } v; v.i = ((unsigned int)u) << 16; return v.f;
}

// ---------------- GEMM: C = A(bf16) @ W(bf16)^T (+bias) (+R) ----------------
// 256x256 tile, BK=64, 8 waves (2M x 4N), K-tile double-buffer with counted
// vmcnt(8) (loads in flight across raw barriers), XOR-swizzled LDS via
// pre-swizzled glds source granule (R3-proven, bank-conflict = 0).
#define BM 256
#define BN 256
#define BK 64

template <int RESID, int OUTM>   // RESID: 0 none, 1 f32, 2 bf16 ; OUTM: 1 f32, 2 bf16
__global__ __launch_bounds__(512, 1) void gemm_bf16(
    const u16* __restrict__ A, const u16* __restrict__ W,
    const float* __restrict__ bias, const void* Rp, void* Optr,
    int M, int N, int K)
{
  __shared__ __align__(16) u16 sA[2][BM * BK];  // 2 x 32 KB
  __shared__ __align__(16) u16 sB[2][BN * BK];  // 2 x 32 KB

  // XCD-aware bijective swizzle (all launches have nwg % 8 == 0)
  const int nbx = gridDim.x;
  const int nwg = nbx * gridDim.y;
  const int orig = blockIdx.y * nbx + blockIdx.x;
  const int cpx = nwg >> 3;
  const int swz = ((nwg & 7) == 0) ? ((orig & 7) * cpx + (orig >> 3)) : orig;
  const int bm = swz / nbx, bn = swz % nbx;

  const int tid = threadIdx.x;
  const int wave = tid >> 6;
  const int lane = tid & 63;
  const int wm = wave >> 2;        // 0..1  (128 rows each)
  const int wn = wave & 3;         // 0..3  (64 cols each)

  const int a_row0 = bm * BM;
  const int w_row0 = bn * BN;

  // staging: chunk c = wave*4+i covers rows [c*8, c*8+8) x 64 cols (1 KB).
  // lane: row r = lane>>3, source granule (lane&7)^r  (XOR swizzle into linear LDS)
  const int st_r = lane >> 3;
  const int st_g = (lane & 7) ^ st_r;
  const size_t st_off = (size_t)st_r * K + st_g * 8;

  f32x4 acc[8][4] = {};

  auto stage = [&](int b, int kt) {
#pragma unroll
    for (int i = 0; i < 4; ++i) {
      const int c = wave * 4 + i;
      __builtin_amdgcn_global_load_lds(
          (gas_cptr)(A + (size_t)(a_row0 + c * 8) * K + kt + st_off),
          (las_ptr)(&sA[b][c * 512]), 16, 0, 0);
    }
#pragma unroll
    for (int i = 0; i < 4; ++i) {
      const int c = wave * 4 + i;
      __builtin_amdgcn_global_load_lds(
          (gas_cptr)(W + (size_t)(w_row0 + c * 8) * K + kt + st_off),
          (las_ptr)(&sB[b][c * 512]), 16, 0, 0);
    }
  };

  const int fr = lane & 15;
  const int l4 = lane >> 4;        // 0..3

  auto compute = [&](int b) {
#pragma unroll
    for (int ks = 0; ks < 2; ++ks) {
      const int gk = ks * 4 + l4;  // granule within 8-granule row
      bf16x8 af[8], bf[4];
#pragma unroll
      for (int m = 0; m < 8; ++m) {
        const int row = wm * 128 + m * 16 + fr;
        af[m] = *(const bf16x8*)&sA[b][row * 64 + (gk ^ (row & 7)) * 8];
      }
#pragma unroll
      for (int n = 0; n < 4; ++n) {
        const int row = wn * 64 + n * 16 + fr;
        bf[n] = *(const bf16x8*)&sB[b][row * 64 + (gk ^ (row & 7)) * 8];
      }
#pragma unroll
      for (int m = 0; m < 8; ++m)
#pragma unroll
        for (int n = 0; n < 4; ++n)
          acc[m][n] = __builtin_amdgcn_mfma_f32_16x16x32_bf16(af[m], bf[n], acc[m][n], 0, 0, 0);
    }
  };

  const int NT = K >> 6;           // K-tiles
  stage(0, 0);                     // prologue: tile 0 in flight
  int buf = 0;
  for (int t = 0; t < NT; ++t) {
    if (t + 1 < NT) {
      stage(buf ^ 1, (t + 1) * BK);            // keep next tile in flight
      asm volatile("s_waitcnt vmcnt(8)" ::: "memory");  // tile t landed
    } else {
      asm volatile("s_waitcnt vmcnt(0)" ::: "memory");
    }
    __builtin_amdgcn_s_barrier();              // raw: no vmcnt(0) drain
    asm volatile("" ::: "memory");
    compute(buf);
    asm volatile("" ::: "memory");
    __builtin_amdgcn_s_barrier();              // all reads of buf done
    buf ^= 1;
  }

  // epilogue: C/D layout col = lane&15, row = (lane>>4)*4 + reg  [m89-verified]
  const float* Rf = (const float*)Rp;
  const u16*   Rb = (const u16*)Rp;
  const int q = l4 * 4;
#pragma unroll
  for (int m = 0; m < 8; ++m) {
#pragma unroll
    for (int j = 0; j < 4; ++j) {
      const size_t rowoff = (size_t)(a_row0 + wm * 128 + m * 16 + q + j) * (size_t)N;
#pragma unroll
      for (int n = 0; n < 4; ++n) {
        const int gc = w_row0 + wn * 64 + n * 16 + fr;
        float v = acc[m][n][j];
        if (bias) v += bias[gc];
        if (RESID == 1) v += Rf[rowoff + gc];
        if (RESID == 2) v += bf2f(Rb[rowoff + gc]);
        if (OUTM == 1) ((float*)Optr)[rowoff + gc] = v;
        else           ((u16*)Optr)[rowoff + gc] = f2bf(v);
      }
    }
  }
}

// ---------------- LayerNorm: bf16 in, optional f32 out + bf16 side-copy -----
template <int OUTF32, int OUTBF16>
__global__ __launch_bounds__(256) void ln_kernel(
    const u16* Y, const float* __restrict__ g, const float* __restrict__ bta,
    float* Of32, u16* Obf)
{
  const int wave = threadIdx.x >> 6, lane = threadIdx.x & 63;
  const size_t row = (size_t)blockIdx.x * 4 + wave;
  const u16* y = Y + row * D_DIM + lane * 16;
  u16x8 v0 = *(const u16x8*)y;
  u16x8 v1 = *(const u16x8*)(y + 8);
  float x[16];
#pragma unroll
  for (int i = 0; i < 8; ++i) { x[i] = bf2f(v0[i]); x[8 + i] = bf2f(v1[i]); }
  float s = 0.f, ss = 0.f;
#pragma unroll
  for (int i = 0; i < 16; ++i) { s += x[i]; ss += x[i] * x[i]; }
#pragma unroll
  for (int off = 32; off > 0; off >>= 1) {
    s += __shfl_xor(s, off, 64);
    ss += __shfl_xor(ss, off, 64);
  }
  const float mean = s * (1.f / 1024.f);
  const float var = ss * (1.f / 1024.f) - mean * mean;
  const float rstd = rsqrtf(var + 1e-5f);
  const int c0 = lane * 16;
  float o[16];
#pragma unroll
  for (int i = 0; i < 16; ++i)
    o[i] = (x[i] - mean) * rstd * g[c0 + i] + bta[c0 + i];
  if (OUTF32) {
    float* p = Of32 + row * D_DIM + c0;
#pragma unroll
    for (int i = 0; i < 4; ++i) {
      f32x4 ov; ov[0] = o[i*4]; ov[1] = o[i*4+1]; ov[2] = o[i*4+2]; ov[3] = o[i*4+3];
      *(f32x4*)(p + i * 4) = ov;
    }
  }
  if (OUTBF16) {
    u16x8 b0, b1;
#pragma unroll
    for (int i = 0; i < 8; ++i) { b0[i] = f2bf(o[i]); b1[i] = f2bf(o[8 + i]); }
    u16* p = Obf + row * D_DIM + c0;
    *(u16x8*)p = b0;
    *(u16x8*)(p + 8) = b1;
  }
}

// ---------------- f32 -> bf16 conversion (grid-stride, 8/thread) -----------
__global__ __launch_bounds__(256) void cvt_kernel(const float* __restrict__ src,
                                                  u16* __restrict__ dst, size_t n)
{
  const size_t stride = (size_t)gridDim.x * 256 * 8;
  for (size_t i = ((size_t)blockIdx.x * 256 + threadIdx.x) * 8; i < n; i += stride) {
    f32x4 a = *(const f32x4*)(src + i);
    f32x4 b = *(const f32x4*)(src + i + 4);
    u16x8 o;
#pragma unroll
    for (int t = 0; t < 4; ++t) { o[t] = f2bf(a[t]); o[t + 4] = f2bf(b[t]); }
    *(u16x8*)(dst + i) = o;
  }
}

struct Ptr4 { const float* s[4]; u16* d[4]; };

__global__ __launch_bounds__(256) void transpose_kernel(Ptr4 p) {
  __shared__ float tile[32][33];
  const int z = blockIdx.z;
  const float* src = p.s[z];
  u16* dst = p.d[z];
  const int tx = threadIdx.x & 31, ty = threadIdx.x >> 5;
  const int gx = blockIdx.x * 32, gy = blockIdx.y * 32;
#pragma unroll
  for (int i = 0; i < 4; ++i) {
    const int r = ty + i * 8;
    tile[r][tx] = src[(size_t)(gy + r) * D_DIM + gx + tx];
  }
  __syncthreads();
#pragma unroll
  for (int i = 0; i < 4; ++i) {
    const int r = ty + i * 8;
    dst[(size_t)(gx + r) * D_DIM + gy + tx] = f2bf(tile[tx][r]);
  }
}

struct BiasArgs { const float* wout[4]; const float* bin[4]; const float* bout[4]; };

__global__ __launch_bounds__(256) void bias_kernel(BiasArgs p, float* cb) {
  const int z = blockIdx.z;
  const int i = blockIdx.x * 256 + threadIdx.x;
  const float* wrow = p.wout[z] + (size_t)i * D_DIM;
  const float* bv = p.bin[z] + 2 * D_DIM;
  float s = 0.f;
  for (int j = 0; j < D_DIM; j += 4) {
    f32x4 w4 = *(const f32x4*)&wrow[j];
    f32x4 b4 = *(const f32x4*)&bv[j];
#pragma unroll
    for (int t = 0; t < 4; ++t) s += w4[t] * b4[t];
  }
  cb[(size_t)z * D_DIM + i] = s + p.bout[z][i];
}

extern "C" void kernel_launch(void* const* d_in, const int* in_sizes, int n_in,
                              void* d_out, int out_size, void* d_ws, size_t ws_size,
                              hipStream_t stream) {
  (void)in_sizes; (void)n_in; (void)out_size; (void)ws_size;
  const size_t BD = (size_t)B_ROWS * D_DIM;
  const size_t DD = (size_t)D_DIM * D_DIM;

  const float* feat_local = (const float*)d_in[0];
  const float* feat_tact  = (const float*)d_in[1];
  const float* feat_strat = (const float*)d_in[2];
  const float* w_in[4]  = {(const float*)d_in[3],  (const float*)d_in[7],  (const float*)d_in[11], (const float*)d_in[15]};
  const float* b_in[4]  = {(const float*)d_in[4],  (const float*)d_in[8],  (const float*)d_in[12], (const float*)d_in[16]};
  const float* w_out[4] = {(const float*)d_in[5],  (const float*)d_in[9],  (const float*)d_in[13], (const float*)d_in[17]};
  const float* b_out[4] = {(const float*)d_in[6],  (const float*)d_in[10], (const float*)d_in[14], (const float*)d_in[18]};
  const float* ln_g[3] = {(const float*)d_in[19], (const float*)d_in[21], (const float*)d_in[23]};
  const float* ln_b[3] = {(const float*)d_in[20], (const float*)d_in[22], (const float*)d_in[24]};

  u16* buf0 = (u16*)d_ws;          // bf16 stream buffers
  u16* buf1 = buf0 + BD;
  u16* wvT  = buf1 + BD;           // 4*DD
  u16* wobf = wvT + 4 * DD;        // 4*DD
  u16* Wc   = wobf + 4 * DD;       // 4*DD
  float* cb = (float*)(Wc + 4 * DD);

  float* out = (float*)d_out;
  float* o_loc = out;
  float* o_tac = out + BD;
  float* o_str = out + 2 * BD;

  // 0. conversions: local -> bf16 (buf0), w_out -> bf16
  hipLaunchKernelGGL(cvt_kernel, dim3(2048), dim3(256), 0, stream, feat_local, buf0, BD);
  for (int z = 0; z < 4; ++z)
    hipLaunchKernelGGL(cvt_kernel, dim3(256), dim3(256), 0, stream, w_out[z], wobf + z * DD, DD);

  // 1. wvT_z = (w_in_z[2D:,:])^T as bf16
  Ptr4 tp;
  for (int z = 0; z < 4; ++z) { tp.s[z] = w_in[z] + 2 * DD; tp.d[z] = wvT + z * DD; }
  hipLaunchKernelGGL(transpose_kernel, dim3(32, 32, 4), dim3(256), 0, stream, tp);

  // 2. combined bias c = w_out*bv + b_out (f32)
  BiasArgs ba;
  for (int z = 0; z < 4; ++z) { ba.wout[z] = w_out[z]; ba.bin[z] = b_in[z]; ba.bout[z] = b_out[z]; }
  hipLaunchKernelGGL(bias_kernel, dim3(4, 1, 4), dim3(256), 0, stream, ba, cb);

  // 3. Wc_z = w_out_z(bf16) @ wvT_z(bf16)^T -> bf16
  for (int z = 0; z < 4; ++z)
    hipLaunchKernelGGL((gemm_bf16<0, 2>), dim3(4, 4), dim3(512), 0, stream,
                       wobf + z * DD, wvT + z * DD, (const float*)nullptr,
                       (const void*)nullptr, (void*)(Wc + z * DD), 1024, 1024, 1024);

  // 4. S1: y1 = lbf @ Wc0^T + c0 + tact(f32) -> buf1 bf16; tacA = LN1(y1) in-place
  hipLaunchKernelGGL((gemm_bf16<1, 2>), dim3(4, 256), dim3(512), 0, stream,
                     buf0, Wc + 0 * DD, cb + 0, (const void*)feat_tact, (void*)buf1,
                     B_ROWS, D_DIM, D_DIM);
  hipLaunchKernelGGL((ln_kernel<0, 1>), dim3(B_ROWS / 4), dim3(256), 0, stream,
                     buf1, ln_g[0], ln_b[0], (float*)nullptr, buf1);

  // 5. S2: y2 = tacA @ Wc1^T + c1 + strat(f32) -> buf0 bf16; LN2 -> strat f32 + bf16
  hipLaunchKernelGGL((gemm_bf16<1, 2>), dim3(4, 256), dim3(512), 0, stream,
                     buf1, Wc + 1 * DD, cb + 1024, (const void*)feat_strat, (void*)buf0,
                     B_ROWS, D_DIM, D_DIM);
  hipLaunchKernelGGL((ln_kernel<1, 1>), dim3(B_ROWS / 4), dim3(256), 0, stream,
                     buf0, ln_g[1], ln_b[1], o_str, buf0);

  // 6. S3: y3 = strat_bf @ Wc2^T + c2 + tacA(bf16) -> buf1 bf16; LN3 -> tac f32 + bf16
  hipLaunchKernelGGL((gemm_bf16<2, 2>), dim3(4, 256), dim3(512), 0, stream,
                     buf0, Wc + 2 * DD, cb + 2048, (const void*)buf1, (void*)buf1,
                     B_ROWS, D_DIM, D_DIM);
  hipLaunchKernelGGL((ln_kernel<1, 1>), dim3(B_ROWS / 4), dim3(256), 0, stream,
                     buf1, ln_g[2], ln_b[2], o_tac, buf1);

  // 7. S4: loc = local(f32) + tacB @ Wc3^T + c3 -> chunk0 f32 (no LN)
  hipLaunchKernelGGL((gemm_bf16<1, 1>), dim3(4, 256), dim3(512), 0, stream,
                     buf1, Wc + 3 * DD, cb + 3072, (const void*)feat_local, (void*)o_loc,
                     B_ROWS, D_DIM, D_DIM);
}

// Round 6
// 2434.152 us; speedup vs baseline: 1.0256x; 1.0256x over previous
//
#include <hip/hip_runtime.h>

#define D_DIM 1024
#define B_ROWS 65536

typedef unsigned short u16;
typedef __attribute__((ext_vector_type(8))) __bf16 bf16x8;
typedef __attribute__((ext_vector_type(4))) float f32x4;
typedef __attribute__((ext_vector_type(8))) unsigned short u16x8;

__device__ __forceinline__ u16 f2bf(float f) {
  union { float fv; unsigned int i; } v; v.fv = f;
  return (u16)((v.i + 0x7FFFu + ((v.i >> 16) & 1u)) >> 16);
}
__device__ __forceinline__ float bf2f(u16 u) {
  union { unsigned int i; float f; } v; v.i = ((unsigned int)u) << 16; return v.f;
}

// ---------------- GEMM: C = A(bf16) @ W(bf16)^T (+bias) (+R) ----------------
// 128x128 tile, BK=64, 4 waves (2x2), 2 blocks/CU. REG-STAGED double buffer:
// global_load -> VGPR (issued before compute, compiler-counted vmcnt) ->
// ds_write after compute -> single __syncthreads per iter. XOR-swizzled LDS
// (write-side swizzle, matching read swizzle; R3/R5-proven conflict-free).
#define BM 128
#define BN 128
#define BK 64
#define TILE_U16 (BM * BK)   // 8192 u16 = 16 KB per operand per buffer

template <int RESID, int OUTM>   // RESID: 0 none, 1 f32, 2 bf16 ; OUTM: 1 f32, 2 bf16
__global__ __launch_bounds__(256, 2) void gemm_bf16(
    const u16* __restrict__ A, const u16* __restrict__ W,
    const float* __restrict__ bias, const void* Rp, void* Optr,
    int M, int N, int K)
{
  __shared__ __align__(16) u16 sA[2][TILE_U16];  // 2 x 16 KB
  __shared__ __align__(16) u16 sB[2][TILE_U16];  // 2 x 16 KB

  // XCD-aware bijective swizzle (all launches have nwg % 8 == 0)
  const int nbx = gridDim.x;
  const int nwg = nbx * gridDim.y;
  const int orig = blockIdx.y * nbx + blockIdx.x;
  const int cpx = nwg >> 3;
  const int swz = ((nwg & 7) == 0) ? ((orig & 7) * cpx + (orig >> 3)) : orig;
  const int bm = swz / nbx, bn = swz % nbx;

  const int tid = threadIdx.x;
  const int wave = tid >> 6;
  const int lane = tid & 63;
  const int wm = wave >> 1, wn = wave & 1;

  const int a_row0 = bm * BM;
  const int w_row0 = bn * BN;

  // staging: chunk i of this wave covers rows [wave*32 + i*8, +8) x 64 cols.
  // lane: row st_r = lane>>3, logical granule st_g = lane&7 (16 B each).
  const int st_r = lane >> 3;
  const int st_g = lane & 7;
  const u16* Ab = A + (size_t)(a_row0 + wave * 32 + st_r) * K + st_g * 8;
  const u16* Wb = W + (size_t)(w_row0 + wave * 32 + st_r) * K + st_g * 8;
  // LDS u16 offset: row*64 + physGranule*8, physGranule = st_g ^ (row&7); row&7 == st_r
  const int w_off = (wave * 32 + st_r) * 64 + ((st_g ^ st_r) * 8);

  u16x8 ra[4], rb[4];
  auto load_regs = [&](int kt) {
#pragma unroll
    for (int i = 0; i < 4; ++i) {
      ra[i] = *(const u16x8*)(Ab + (size_t)i * 8 * K + kt);
      rb[i] = *(const u16x8*)(Wb + (size_t)i * 8 * K + kt);
    }
  };
  auto write_lds = [&](int b) {
#pragma unroll
    for (int i = 0; i < 4; ++i) {
      *(u16x8*)&sA[b][w_off + i * 512] = ra[i];
      *(u16x8*)&sB[b][w_off + i * 512] = rb[i];
    }
  };

  f32x4 acc[4][4] = {};
  const int fr = lane & 15;
  const int l4 = lane >> 4;

  auto compute = [&](int b) {
#pragma unroll
    for (int ks = 0; ks < 2; ++ks) {
      const int gk = ks * 4 + l4;   // logical granule 0..7 within the 128B row
      bf16x8 af[4], bf[4];
#pragma unroll
      for (int m = 0; m < 4; ++m) {
        const int row = wm * 64 + m * 16 + fr;
        af[m] = *(const bf16x8*)&sA[b][row * 64 + ((gk ^ (row & 7)) * 8)];
      }
#pragma unroll
      for (int n = 0; n < 4; ++n) {
        const int row = wn * 64 + n * 16 + fr;
        bf[n] = *(const bf16x8*)&sB[b][row * 64 + ((gk ^ (row & 7)) * 8)];
      }
#pragma unroll
      for (int m = 0; m < 4; ++m)
#pragma unroll
        for (int n = 0; n < 4; ++n)
          acc[m][n] = __builtin_amdgcn_mfma_f32_16x16x32_bf16(af[m], bf[n], acc[m][n], 0, 0, 0);
    }
  };

  const int NT = K >> 6;
  // prologue: tile 0
  load_regs(0);
  write_lds(0);
  __syncthreads();
  int buf = 0;
  for (int t = 0; t < NT; ++t) {
    if (t + 1 < NT) load_regs((t + 1) * BK);   // in flight across compute
    compute(buf);
    if (t + 1 < NT) {
      write_lds(buf ^ 1);    // compiler inserts counted vmcnt for ra/rb here
      __syncthreads();       // vmcnt already drained -> cheap
    }
    buf ^= 1;
  }

  // epilogue: C/D layout col = lane&15, row = (lane>>4)*4 + reg  [m89-verified]
  const float* Rf = (const float*)Rp;
  const u16*   Rb = (const u16*)Rp;
  const int q = l4 * 4;
#pragma unroll
  for (int m = 0; m < 4; ++m) {
#pragma unroll
    for (int j = 0; j < 4; ++j) {
      const size_t rowoff = (size_t)(a_row0 + wm * 64 + m * 16 + q + j) * (size_t)N;
#pragma unroll
      for (int n = 0; n < 4; ++n) {
        const int gc = w_row0 + wn * 64 + n * 16 + fr;
        float v = acc[m][n][j];
        if (bias) v += bias[gc];
        if (RESID == 1) v += Rf[rowoff + gc];
        if (RESID == 2) v += bf2f(Rb[rowoff + gc]);
        if (OUTM == 1) ((float*)Optr)[rowoff + gc] = v;
        else           ((u16*)Optr)[rowoff + gc] = f2bf(v);
      }
    }
  }
}

// ---------------- LayerNorm: bf16 in, optional f32 out + bf16 side-copy -----
template <int OUTF32, int OUTBF16>
__global__ __launch_bounds__(256) void ln_kernel(
    const u16* Y, const float* __restrict__ g, const float* __restrict__ bta,
    float* Of32, u16* Obf)
{
  const int wave = threadIdx.x >> 6, lane = threadIdx.x & 63;
  const size_t row = (size_t)blockIdx.x * 4 + wave;
  const u16* y = Y + row * D_DIM + lane * 16;
  u16x8 v0 = *(const u16x8*)y;
  u16x8 v1 = *(const u16x8*)(y + 8);
  float x[16];
#pragma unroll
  for (int i = 0; i < 8; ++i) { x[i] = bf2f(v0[i]); x[8 + i] = bf2f(v1[i]); }
  float s = 0.f, ss = 0.f;
#pragma unroll
  for (int i = 0; i < 16; ++i) { s += x[i]; ss += x[i] * x[i]; }
#pragma unroll
  for (int off = 32; off > 0; off >>= 1) {
    s += __shfl_xor(s, off, 64);
    ss += __shfl_xor(ss, off, 64);
  }
  const float mean = s * (1.f / 1024.f);
  const float var = ss * (1.f / 1024.f) - mean * mean;
  const float rstd = rsqrtf(var + 1e-5f);
  const int c0 = lane * 16;
  float o[16];
#pragma unroll
  for (int i = 0; i < 16; ++i)
    o[i] = (x[i] - mean) * rstd * g[c0 + i] + bta[c0 + i];
  if (OUTF32) {
    float* p = Of32 + row * D_DIM + c0;
#pragma unroll
    for (int i = 0; i < 4; ++i) {
      f32x4 ov; ov[0] = o[i*4]; ov[1] = o[i*4+1]; ov[2] = o[i*4+2]; ov[3] = o[i*4+3];
      *(f32x4*)(p + i * 4) = ov;
    }
  }
  if (OUTBF16) {
    u16x8 b0, b1;
#pragma unroll
    for (int i = 0; i < 8; ++i) { b0[i] = f2bf(o[i]); b1[i] = f2bf(o[8 + i]); }
    u16* p = Obf + row * D_DIM + c0;
    *(u16x8*)p = b0;
    *(u16x8*)(p + 8) = b1;
  }
}

// ---------------- f32 -> bf16 conversion (grid-stride, 8/thread) -----------
__global__ __launch_bounds__(256) void cvt_kernel(const float* __restrict__ src,
                                                  u16* __restrict__ dst, size_t n)
{
  const size_t stride = (size_t)gridDim.x * 256 * 8;
  for (size_t i = ((size_t)blockIdx.x * 256 + threadIdx.x) * 8; i < n; i += stride) {
    f32x4 a = *(const f32x4*)(src + i);
    f32x4 b = *(const f32x4*)(src + i + 4);
    u16x8 o;
#pragma unroll
    for (int t = 0; t < 4; ++t) { o[t] = f2bf(a[t]); o[t + 4] = f2bf(b[t]); }
    *(u16x8*)(dst + i) = o;
  }
}

struct Ptr4 { const float* s[4]; u16* d[4]; };

__global__ __launch_bounds__(256) void transpose_kernel(Ptr4 p) {
  __shared__ float tile[32][33];
  const int z = blockIdx.z;
  const float* src = p.s[z];
  u16* dst = p.d[z];
  const int tx = threadIdx.x & 31, ty = threadIdx.x >> 5;
  const int gx = blockIdx.x * 32, gy = blockIdx.y * 32;
#pragma unroll
  for (int i = 0; i < 4; ++i) {
    const int r = ty + i * 8;
    tile[r][tx] = src[(size_t)(gy + r) * D_DIM + gx + tx];
  }
  __syncthreads();
#pragma unroll
  for (int i = 0; i < 4; ++i) {
    const int r = ty + i * 8;
    dst[(size_t)(gx + r) * D_DIM + gy + tx] = f2bf(tile[tx][r]);
  }
}

struct BiasArgs { const float* wout[4]; const float* bin[4]; const float* bout[4]; };

__global__ __launch_bounds__(256) void bias_kernel(BiasArgs p, float* cb) {
  const int z = blockIdx.z;
  const int i = blockIdx.x * 256 + threadIdx.x;
  const float* wrow = p.wout[z] + (size_t)i * D_DIM;
  const float* bv = p.bin[z] + 2 * D_DIM;
  float s = 0.f;
  for (int j = 0; j < D_DIM; j += 4) {
    f32x4 w4 = *(const f32x4*)&wrow[j];
    f32x4 b4 = *(const f32x4*)&bv[j];
#pragma unroll
    for (int t = 0; t < 4; ++t) s += w4[t] * b4[t];
  }
  cb[(size_t)z * D_DIM + i] = s + p.bout[z][i];
}

extern "C" void kernel_launch(void* const* d_in, const int* in_sizes, int n_in,
                              void* d_out, int out_size, void* d_ws, size_t ws_size,
                              hipStream_t stream) {
  (void)in_sizes; (void)n_in; (void)out_size; (void)ws_size;
  const size_t BD = (size_t)B_ROWS * D_DIM;
  const size_t DD = (size_t)D_DIM * D_DIM;

  const float* feat_local = (const float*)d_in[0];
  const float* feat_tact  = (const float*)d_in[1];
  const float* feat_strat = (const float*)d_in[2];
  const float* w_in[4]  = {(const float*)d_in[3],  (const float*)d_in[7],  (const float*)d_in[11], (const float*)d_in[15]};
  const float* b_in[4]  = {(const float*)d_in[4],  (const float*)d_in[8],  (const float*)d_in[12], (const float*)d_in[16]};
  const float* w_out[4] = {(const float*)d_in[5],  (const float*)d_in[9],  (const float*)d_in[13], (const float*)d_in[17]};
  const float* b_out[4] = {(const float*)d_in[6],  (const float*)d_in[10], (const float*)d_in[14], (const float*)d_in[18]};
  const float* ln_g[3] = {(const float*)d_in[19], (const float*)d_in[21], (const float*)d_in[23]};
  const float* ln_b[3] = {(const float*)d_in[20], (const float*)d_in[22], (const float*)d_in[24]};

  u16* buf0 = (u16*)d_ws;          // bf16 stream buffers
  u16* buf1 = buf0 + BD;
  u16* wvT  = buf1 + BD;           // 4*DD
  u16* wobf = wvT + 4 * DD;        // 4*DD
  u16* Wc   = wobf + 4 * DD;       // 4*DD
  float* cb = (float*)(Wc + 4 * DD);

  float* out = (float*)d_out;
  float* o_loc = out;
  float* o_tac = out + BD;
  float* o_str = out + 2 * BD;

  // 0. conversions: local -> bf16 (buf0), w_out -> bf16
  hipLaunchKernelGGL(cvt_kernel, dim3(2048), dim3(256), 0, stream, feat_local, buf0, BD);
  for (int z = 0; z < 4; ++z)
    hipLaunchKernelGGL(cvt_kernel, dim3(256), dim3(256), 0, stream, w_out[z], wobf + z * DD, DD);

  // 1. wvT_z = (w_in_z[2D:,:])^T as bf16
  Ptr4 tp;
  for (int z = 0; z < 4; ++z) { tp.s[z] = w_in[z] + 2 * DD; tp.d[z] = wvT + z * DD; }
  hipLaunchKernelGGL(transpose_kernel, dim3(32, 32, 4), dim3(256), 0, stream, tp);

  // 2. combined bias c = w_out*bv + b_out (f32)
  BiasArgs ba;
  for (int z = 0; z < 4; ++z) { ba.wout[z] = w_out[z]; ba.bin[z] = b_in[z]; ba.bout[z] = b_out[z]; }
  hipLaunchKernelGGL(bias_kernel, dim3(4, 1, 4), dim3(256), 0, stream, ba, cb);

  // 3. Wc_z = w_out_z(bf16) @ wvT_z(bf16)^T -> bf16
  for (int z = 0; z < 4; ++z)
    hipLaunchKernelGGL((gemm_bf16<0, 2>), dim3(8, 8), dim3(256), 0, stream,
                       wobf + z * DD, wvT + z * DD, (const float*)nullptr,
                       (const void*)nullptr, (void*)(Wc + z * DD), 1024, 1024, 1024);

  // 4. S1: y1 = lbf @ Wc0^T + c0 + tact(f32) -> buf1 bf16; tacA = LN1(y1) in-place
  hipLaunchKernelGGL((gemm_bf16<1, 2>), dim3(8, 512), dim3(256), 0, stream,
                     buf0, Wc + 0 * DD, cb + 0, (const void*)feat_tact, (void*)buf1,
                     B_ROWS, D_DIM, D_DIM);
  hipLaunchKernelGGL((ln_kernel<0, 1>), dim3(B_ROWS / 4), dim3(256), 0, stream,
                     buf1, ln_g[0], ln_b[0], (float*)nullptr, buf1);

  // 5. S2: y2 = tacA @ Wc1^T + c1 + strat(f32) -> buf0 bf16; LN2 -> strat f32 + bf16
  hipLaunchKernelGGL((gemm_bf16<1, 2>), dim3(8, 512), dim3(256), 0, stream,
                     buf1, Wc + 1 * DD, cb + 1024, (const void*)feat_strat, (void*)buf0,
                     B_ROWS, D_DIM, D_DIM);
  hipLaunchKernelGGL((ln_kernel<1, 1>), dim3(B_ROWS / 4), dim3(256), 0, stream,
                     buf0, ln_g[1], ln_b[1], o_str, buf0);

  // 6. S3: y3 = strat_bf @ Wc2^T + c2 + tacA(bf16) -> buf1 bf16; LN3 -> tac f32 + bf16
  hipLaunchKernelGGL((gemm_bf16<2, 2>), dim3(8, 512), dim3(256), 0, stream,
                     buf0, Wc + 2 * DD, cb + 2048, (const void*)buf1, (void*)buf1,
                     B_ROWS, D_DIM, D_DIM);
  hipLaunchKernelGGL((ln_kernel<1, 1>), dim3(B_ROWS / 4), dim3(256), 0, stream,
                     buf1, ln_g[2], ln_b[2], o_tac, buf1);

  // 7. S4: loc = local(f32) + tacB @ Wc3^T + c3 -> chunk0 f32 (no LN)
  hipLaunchKernelGGL((gemm_bf16<1, 1>), dim3(8, 512), dim3(256), 0, stream,
                     buf1, Wc + 3 * DD, cb + 3072, (const void*)feat_local, (void*)o_loc,
                     B_ROWS, D_DIM, D_DIM);
}

// Round 7
// 2190.085 us; speedup vs baseline: 1.1399x; 1.1114x over previous
//
#include <hip/hip_runtime.h>

#define D_DIM 1024
#define B_ROWS 65536

typedef unsigned short u16;
typedef __attribute__((ext_vector_type(8))) __bf16 bf16x8;
typedef __attribute__((ext_vector_type(4))) float f32x4;
typedef __attribute__((ext_vector_type(8))) unsigned short u16x8;

__device__ __forceinline__ u16 f2bf(float f) {
  union { float fv; unsigned int i; } v; v.fv = f;
  return (u16)((v.i + 0x7FFFu + ((v.i >> 16) & 1u)) >> 16);
}
__device__ __forceinline__ float bf2f(u16 u) {
  union { unsigned int i; float f; } v; v.i = ((unsigned int)u) << 16; return v.f;
}

// ---------------- GEMM: C = A(bf16) @ W(bf16)^T (+bias) (+R) ----------------
// 128x128 tile, BK=32, 4 waves (2x2), 3 blocks/CU, DEPTH-2 register prefetch:
// loads for tile t+2 issued at iter t (two named reg sets), ds_write at iter
// t+1 -> vmcnt wait sees ~1.5 iters of aging. XOR-swizzled LDS (conflict-free).
#define BM 128
#define BN 128
#define BK 32
#define TILE_U16 (BM * BK)   // 4096 u16 = 8 KB per operand per buffer

template <int RESID, int OUTM>   // RESID: 0 none, 1 f32, 2 bf16 ; OUTM: 1 f32, 2 bf16
__global__ __launch_bounds__(256, 3) void gemm_bf16(
    const u16* __restrict__ A, const u16* __restrict__ W,
    const float* __restrict__ bias, const void* Rp, void* Optr,
    int M, int N, int K)
{
  __shared__ __align__(16) u16 sA[2][TILE_U16];  // 2 x 8 KB
  __shared__ __align__(16) u16 sB[2][TILE_U16];  // 2 x 8 KB

  // XCD-aware bijective swizzle (all launches have nwg % 8 == 0)
  const int nbx = gridDim.x;
  const int nwg = nbx * gridDim.y;
  const int orig = blockIdx.y * nbx + blockIdx.x;
  const int cpx = nwg >> 3;
  const int swz = ((nwg & 7) == 0) ? ((orig & 7) * cpx + (orig >> 3)) : orig;
  const int bm = swz / nbx, bn = swz % nbx;

  const int tid = threadIdx.x;
  const int wave = tid >> 6;
  const int lane = tid & 63;
  const int wm = wave >> 1, wn = wave & 1;

  const int a_row0 = bm * BM;
  const int w_row0 = bn * BN;

  // staging: per wave 2 loads/operand; load i covers rows [wave*32+i*16, +16) x 32 cols.
  // lane: row = i*16 + (lane>>2), logical granule lg = lane&3 (16 B each).
  const int st_r = lane >> 2;          // 0..15
  const int st_lg = lane & 3;
  const u16* Ab = A + (size_t)(a_row0 + wave * 32 + st_r) * K + st_lg * 8;
  const u16* Wb = W + (size_t)(w_row0 + wave * 32 + st_r) * K + st_lg * 8;
  // LDS u16 offset (swizzled): row*32 + ((lg ^ (row&3)))*8
  const int st_row = wave * 32 + st_r;
  const int w_off = st_row * 32 + ((st_lg ^ (st_row & 3)) * 8);

  u16x8 s0[4], s1[4];   // two named prefetch sets: [a0,a1,b0,b1]
  auto load_set0 = [&](int kt) {
    s0[0] = *(const u16x8*)(Ab + kt);
    s0[1] = *(const u16x8*)(Ab + (size_t)16 * K + kt);
    s0[2] = *(const u16x8*)(Wb + kt);
    s0[3] = *(const u16x8*)(Wb + (size_t)16 * K + kt);
  };
  auto load_set1 = [&](int kt) {
    s1[0] = *(const u16x8*)(Ab + kt);
    s1[1] = *(const u16x8*)(Ab + (size_t)16 * K + kt);
    s1[2] = *(const u16x8*)(Wb + kt);
    s1[3] = *(const u16x8*)(Wb + (size_t)16 * K + kt);
  };
  auto write_set0 = [&](int b) {
    *(u16x8*)&sA[b][w_off] = s0[0];
    *(u16x8*)&sA[b][w_off + 16 * 32] = s0[1];
    *(u16x8*)&sB[b][w_off] = s0[2];
    *(u16x8*)&sB[b][w_off + 16 * 32] = s0[3];
  };
  auto write_set1 = [&](int b) {
    *(u16x8*)&sA[b][w_off] = s1[0];
    *(u16x8*)&sA[b][w_off + 16 * 32] = s1[1];
    *(u16x8*)&sB[b][w_off] = s1[2];
    *(u16x8*)&sB[b][w_off + 16 * 32] = s1[3];
  };

  f32x4 acc[4][4] = {};
  const int fr = lane & 15;
  const int l4 = lane >> 4;            // logical granule for fragment reads

  auto compute = [&](int b) {
    bf16x8 af[4], bf[4];
#pragma unroll
    for (int m = 0; m < 4; ++m) {
      const int row = wm * 64 + m * 16 + fr;
      af[m] = *(const bf16x8*)&sA[b][row * 32 + ((l4 ^ (row & 3)) * 8)];
    }
#pragma unroll
    for (int n = 0; n < 4; ++n) {
      const int row = wn * 64 + n * 16 + fr;
      bf[n] = *(const bf16x8*)&sB[b][row * 32 + ((l4 ^ (row & 3)) * 8)];
    }
#pragma unroll
    for (int m = 0; m < 4; ++m)
#pragma unroll
      for (int n = 0; n < 4; ++n)
        acc[m][n] = __builtin_amdgcn_mfma_f32_16x16x32_bf16(af[m], bf[n], acc[m][n], 0, 0, 0);
  };

  const int NT = K >> 5;    // 32 for K=1024 (even)
  // prologue: tiles 0,1 in flight; tile 0 into LDS buf0
  load_set0(0);
  load_set1(BK);
  write_set0(0);
  __syncthreads();

  for (int t = 0; t < NT; t += 2) {
    // even phase: compute buf0, write tile t+1 (s1) -> buf1
    if (t + 2 < NT) load_set0((t + 2) * BK);
    compute(0);
    if (t + 1 < NT) {
      write_set1(1);
      __syncthreads();
    }
    // odd phase: compute buf1, write tile t+2 (s0) -> buf0
    if (t + 1 < NT) {
      if (t + 3 < NT) load_set1((t + 3) * BK);
      compute(1);
      if (t + 2 < NT) {
        write_set0(0);
        __syncthreads();
      }
    }
  }

  // epilogue: C/D layout col = lane&15, row = (lane>>4)*4 + reg  [m89-verified]
  const float* Rf = (const float*)Rp;
  const u16*   Rb = (const u16*)Rp;
  const int q = l4 * 4;
#pragma unroll
  for (int m = 0; m < 4; ++m) {
#pragma unroll
    for (int j = 0; j < 4; ++j) {
      const size_t rowoff = (size_t)(a_row0 + wm * 64 + m * 16 + q + j) * (size_t)N;
#pragma unroll
      for (int n = 0; n < 4; ++n) {
        const int gc = w_row0 + wn * 64 + n * 16 + fr;
        float v = acc[m][n][j];
        if (bias) v += bias[gc];
        if (RESID == 1) v += Rf[rowoff + gc];
        if (RESID == 2) v += bf2f(Rb[rowoff + gc]);
        if (OUTM == 1) ((float*)Optr)[rowoff + gc] = v;
        else           ((u16*)Optr)[rowoff + gc] = f2bf(v);
      }
    }
  }
}

// ---------------- LayerNorm: bf16 in, optional f32 out + bf16 side-copy -----
template <int OUTF32, int OUTBF16>
__global__ __launch_bounds__(256) void ln_kernel(
    const u16* Y, const float* __restrict__ g, const float* __restrict__ bta,
    float* Of32, u16* Obf)
{
  const int wave = threadIdx.x >> 6, lane = threadIdx.x & 63;
  const size_t row = (size_t)blockIdx.x * 4 + wave;
  const u16* y = Y + row * D_DIM + lane * 16;
  u16x8 v0 = *(const u16x8*)y;
  u16x8 v1 = *(const u16x8*)(y + 8);
  float x[16];
#pragma unroll
  for (int i = 0; i < 8; ++i) { x[i] = bf2f(v0[i]); x[8 + i] = bf2f(v1[i]); }
  float s = 0.f, ss = 0.f;
#pragma unroll
  for (int i = 0; i < 16; ++i) { s += x[i]; ss += x[i] * x[i]; }
#pragma unroll
  for (int off = 32; off > 0; off >>= 1) {
    s += __shfl_xor(s, off, 64);
    ss += __shfl_xor(ss, off, 64);
  }
  const float mean = s * (1.f / 1024.f);
  const float var = ss * (1.f / 1024.f) - mean * mean;
  const float rstd = rsqrtf(var + 1e-5f);
  const int c0 = lane * 16;
  float o[16];
#pragma unroll
  for (int i = 0; i < 16; ++i)
    o[i] = (x[i] - mean) * rstd * g[c0 + i] + bta[c0 + i];
  if (OUTF32) {
    float* p = Of32 + row * D_DIM + c0;
#pragma unroll
    for (int i = 0; i < 4; ++i) {
      f32x4 ov; ov[0] = o[i*4]; ov[1] = o[i*4+1]; ov[2] = o[i*4+2]; ov[3] = o[i*4+3];
      *(f32x4*)(p + i * 4) = ov;
    }
  }
  if (OUTBF16) {
    u16x8 b0, b1;
#pragma unroll
    for (int i = 0; i < 8; ++i) { b0[i] = f2bf(o[i]); b1[i] = f2bf(o[8 + i]); }
    u16* p = Obf + row * D_DIM + c0;
    *(u16x8*)p = b0;
    *(u16x8*)(p + 8) = b1;
  }
}

// ---------------- f32 -> bf16 conversion (grid-stride, 8/thread) -----------
__global__ __launch_bounds__(256) void cvt_kernel(const float* __restrict__ src,
                                                  u16* __restrict__ dst, size_t n)
{
  const size_t stride = (size_t)gridDim.x * 256 * 8;
  for (size_t i = ((size_t)blockIdx.x * 256 + threadIdx.x) * 8; i < n; i += stride) {
    f32x4 a = *(const f32x4*)(src + i);
    f32x4 b = *(const f32x4*)(src + i + 4);
    u16x8 o;
#pragma unroll
    for (int t = 0; t < 4; ++t) { o[t] = f2bf(a[t]); o[t + 4] = f2bf(b[t]); }
    *(u16x8*)(dst + i) = o;
  }
}

struct Ptr4 { const float* s[4]; u16* d[4]; };

__global__ __launch_bounds__(256) void transpose_kernel(Ptr4 p) {
  __shared__ float tile[32][33];
  const int z = blockIdx.z;
  const float* src = p.s[z];
  u16* dst = p.d[z];
  const int tx = threadIdx.x & 31, ty = threadIdx.x >> 5;
  const int gx = blockIdx.x * 32, gy = blockIdx.y * 32;
#pragma unroll
  for (int i = 0; i < 4; ++i) {
    const int r = ty + i * 8;
    tile[r][tx] = src[(size_t)(gy + r) * D_DIM + gx + tx];
  }
  __syncthreads();
#pragma unroll
  for (int i = 0; i < 4; ++i) {
    const int r = ty + i * 8;
    dst[(size_t)(gx + r) * D_DIM + gy + tx] = f2bf(tile[tx][r]);
  }
}

struct BiasArgs { const float* wout[4]; const float* bin[4]; const float* bout[4]; };

__global__ __launch_bounds__(256) void bias_kernel(BiasArgs p, float* cb) {
  const int z = blockIdx.z;
  const int i = blockIdx.x * 256 + threadIdx.x;
  const float* wrow = p.wout[z] + (size_t)i * D_DIM;
  const float* bv = p.bin[z] + 2 * D_DIM;
  float s = 0.f;
  for (int j = 0; j < D_DIM; j += 4) {
    f32x4 w4 = *(const f32x4*)&wrow[j];
    f32x4 b4 = *(const f32x4*)&bv[j];
#pragma unroll
    for (int t = 0; t < 4; ++t) s += w4[t] * b4[t];
  }
  cb[(size_t)z * D_DIM + i] = s + p.bout[z][i];
}

extern "C" void kernel_launch(void* const* d_in, const int* in_sizes, int n_in,
                              void* d_out, int out_size, void* d_ws, size_t ws_size,
                              hipStream_t stream) {
  (void)in_sizes; (void)n_in; (void)out_size; (void)ws_size;
  const size_t BD = (size_t)B_ROWS * D_DIM;
  const size_t DD = (size_t)D_DIM * D_DIM;

  const float* feat_local = (const float*)d_in[0];
  const float* feat_tact  = (const float*)d_in[1];
  const float* feat_strat = (const float*)d_in[2];
  const float* w_in[4]  = {(const float*)d_in[3],  (const float*)d_in[7],  (const float*)d_in[11], (const float*)d_in[15]};
  const float* b_in[4]  = {(const float*)d_in[4],  (const float*)d_in[8],  (const float*)d_in[12], (const float*)d_in[16]};
  const float* w_out[4] = {(const float*)d_in[5],  (const float*)d_in[9],  (const float*)d_in[13], (const float*)d_in[17]};
  const float* b_out[4] = {(const float*)d_in[6],  (const float*)d_in[10], (const float*)d_in[14], (const float*)d_in[18]};
  const float* ln_g[3] = {(const float*)d_in[19], (const float*)d_in[21], (const float*)d_in[23]};
  const float* ln_b[3] = {(const float*)d_in[20], (const float*)d_in[22], (const float*)d_in[24]};

  u16* buf0 = (u16*)d_ws;          // bf16 stream buffers
  u16* buf1 = buf0 + BD;
  u16* wvT  = buf1 + BD;           // 4*DD
  u16* wobf = wvT + 4 * DD;        // 4*DD
  u16* Wc   = wobf + 4 * DD;       // 4*DD
  float* cb = (float*)(Wc + 4 * DD);

  float* out = (float*)d_out;
  float* o_loc = out;
  float* o_tac = out + BD;
  float* o_str = out + 2 * BD;

  // 0. conversions: local -> bf16 (buf0), w_out -> bf16
  hipLaunchKernelGGL(cvt_kernel, dim3(2048), dim3(256), 0, stream, feat_local, buf0, BD);
  for (int z = 0; z < 4; ++z)
    hipLaunchKernelGGL(cvt_kernel, dim3(256), dim3(256), 0, stream, w_out[z], wobf + z * DD, DD);

  // 1. wvT_z = (w_in_z[2D:,:])^T as bf16
  Ptr4 tp;
  for (int z = 0; z < 4; ++z) { tp.s[z] = w_in[z] + 2 * DD; tp.d[z] = wvT + z * DD; }
  hipLaunchKernelGGL(transpose_kernel, dim3(32, 32, 4), dim3(256), 0, stream, tp);

  // 2. combined bias c = w_out*bv + b_out (f32)
  BiasArgs ba;
  for (int z = 0; z < 4; ++z) { ba.wout[z] = w_out[z]; ba.bin[z] = b_in[z]; ba.bout[z] = b_out[z]; }
  hipLaunchKernelGGL(bias_kernel, dim3(4, 1, 4), dim3(256), 0, stream, ba, cb);

  // 3. Wc_z = w_out_z(bf16) @ wvT_z(bf16)^T -> bf16
  for (int z = 0; z < 4; ++z)
    hipLaunchKernelGGL((gemm_bf16<0, 2>), dim3(8, 8), dim3(256), 0, stream,
                       wobf + z * DD, wvT + z * DD, (const float*)nullptr,
                       (const void*)nullptr, (void*)(Wc + z * DD), 1024, 1024, 1024);

  // 4. S1: y1 = lbf @ Wc0^T + c0 + tact(f32) -> buf1 bf16; tacA = LN1(y1) in-place
  hipLaunchKernelGGL((gemm_bf16<1, 2>), dim3(8, 512), dim3(256), 0, stream,
                     buf0, Wc + 0 * DD, cb + 0, (const void*)feat_tact, (void*)buf1,
                     B_ROWS, D_DIM, D_DIM);
  hipLaunchKernelGGL((ln_kernel<0, 1>), dim3(B_ROWS / 4), dim3(256), 0, stream,
                     buf1, ln_g[0], ln_b[0], (float*)nullptr, buf1);

  // 5. S2: y2 = tacA @ Wc1^T + c1 + strat(f32) -> buf0 bf16; LN2 -> strat f32 + bf16
  hipLaunchKernelGGL((gemm_bf16<1, 2>), dim3(8, 512), dim3(256), 0, stream,
                     buf1, Wc + 1 * DD, cb + 1024, (const void*)feat_strat, (void*)buf0,
                     B_ROWS, D_DIM, D_DIM);
  hipLaunchKernelGGL((ln_kernel<1, 1>), dim3(B_ROWS / 4), dim3(256), 0, stream,
                     buf0, ln_g[1], ln_b[1], o_str, buf0);

  // 6. S3: y3 = strat_bf @ Wc2^T + c2 + tacA(bf16) -> buf1 bf16; LN3 -> tac f32 + bf16
  hipLaunchKernelGGL((gemm_bf16<2, 2>), dim3(8, 512), dim3(256), 0, stream,
                     buf0, Wc + 2 * DD, cb + 2048, (const void*)buf1, (void*)buf1,
                     B_ROWS, D_DIM, D_DIM);
  hipLaunchKernelGGL((ln_kernel<1, 1>), dim3(B_ROWS / 4), dim3(256), 0, stream,
                     buf1, ln_g[2], ln_b[2], o_tac, buf1);

  // 7. S4: loc = local(f32) + tacB @ Wc3^T + c3 -> chunk0 f32 (no LN)
  hipLaunchKernelGGL((gemm_bf16<1, 1>), dim3(8, 512), dim3(256), 0, stream,
                     buf1, Wc + 3 * DD, cb + 3072, (const void*)feat_local, (void*)o_loc,
                     B_ROWS, D_DIM, D_DIM);
}